// Round 6
// baseline (240.214 us; speedup 1.0000x reference)
//
#include <hip/hip_runtime.h>

// LJ constants (sigma=1, eps=1, cutoff=5)
// SHIFT = 4*((1/5)^12 - (1/5)^6)
__device__ __constant__ float kShift = 4.0f * (float)(1.0 / 244140625.0 - 1.0 / 15625.0);

#define GROUPS 3
#define MAX_MEMBERS 84             // 3*84 = 252 blocks; partials 33.6 MB + gacc 0.4 MB = 34.0 MB ws
#define BUCKET 33334               // atoms per group; 133,336 B LDS (1 block/CU)
#define BLOCK_T 1024               // 16 waves
#define GFRAC 9                    // 1/9 of quads routed to the global-atomic (EA) pipe

// Bottleneck model (R3/R4/R5 fit): LDS atomic unit = ~4 cyc per active lane-add,
// per CU, independent of bucket size / fetch traffic / ILP. 12.8M adds on LDS
// alone => ~83 us floor. The EA global-atomic pipe runs at ~19.2 G adds/s
// (measured R1) and is INDEPENDENT of the LDS unit => split adds across both:
// LDS (8/9)*84us  ||  EA (1/9)*666us ~= 74us each, overlapped.

__device__ __forceinline__ float lj_half_e(float x, float y, float z) {
    float r2 = x * x + y * y + z * z;
    float inv_r2 = 1.0f / r2;
    float sr6 = inv_r2 * inv_r2 * inv_r2;   // (sigma/r)^6
    float sr12 = sr6 * sr6;
    float e = 4.0f * (sr12 - sr6) - kShift;
    return 0.5f * e;
}

__global__ __launch_bounds__(BLOCK_T) void lj_gather_hybrid(
        const float* __restrict__ dist,
        const int* __restrict__ atom_a,
        const int* __restrict__ atom_b,
        float* __restrict__ ws,       // partials [GROUPS*members][BUCKET]
        float* __restrict__ gacc,     // global-atomic accumulator [n_atoms], pre-zeroed
        int members, int n_edges) {
    __shared__ float acc[BUCKET];

    const int g = blockIdx.x / members;     // group: atom range owner
    const int m = blockIdx.x % members;     // slice: edge range
    const unsigned lo = (unsigned)(g * BUCKET);

    for (int i = threadIdx.x; i < BUCKET; i += BLOCK_T) acc[i] = 0.0f;
    __syncthreads();

    const long long quads = (long long)n_edges >> 2;
    const long long per = (quads + members - 1) / members;
    const long long q0 = (long long)m * per;
    const long long qe = (q0 + per < quads) ? (q0 + per) : quads;
    const long long span = (qe > q0) ? (qe - q0) : 0;
    const long long gq = span / GFRAC;      // quads handled via global atomics

    // ---- Global-atomic phase (designated group only; issued FIRST so the
    // ---- EA drain overlaps the whole LDS phase). All 8 endpoint adds go
    // ---- straight to gacc; the other two groups skip these quads entirely.
    if ((m % GROUPS) == g) {
        for (long long q = q0 + threadIdx.x; q < q0 + gq; q += BLOCK_T) {
            const float4* d4 = (const float4*)(dist) + (size_t)q * 3;
            float4 v0 = d4[0];
            float4 v1 = d4[1];
            float4 v2 = d4[2];
            int4 ia = ((const int4*)atom_a)[q];
            int4 ib = ((const int4*)atom_b)[q];
            float h0 = lj_half_e(v0.x, v0.y, v0.z);
            float h1 = lj_half_e(v0.w, v1.x, v1.y);
            float h2 = lj_half_e(v1.z, v1.w, v2.x);
            float h3 = lj_half_e(v2.y, v2.z, v2.w);
            atomicAdd(&gacc[ia.x], h0);
            atomicAdd(&gacc[ib.x], h0);
            atomicAdd(&gacc[ia.y], h1);
            atomicAdd(&gacc[ib.y], h1);
            atomicAdd(&gacc[ia.z], h2);
            atomicAdd(&gacc[ib.z], h2);
            atomicAdd(&gacc[ia.w], h3);
            atomicAdd(&gacc[ib.w], h3);
        }
    }

    // ---- LDS-atomic phase: remaining 8/9 of the slice, bucket-predicated.
    for (long long q = q0 + gq + threadIdx.x; q < qe; q += BLOCK_T) {
        const float4* d4 = (const float4*)(dist) + (size_t)q * 3;
        float4 v0 = d4[0];
        float4 v1 = d4[1];
        float4 v2 = d4[2];
        int4 ia = ((const int4*)atom_a)[q];
        int4 ib = ((const int4*)atom_b)[q];

        float h0 = lj_half_e(v0.x, v0.y, v0.z);
        float h1 = lj_half_e(v0.w, v1.x, v1.y);
        float h2 = lj_half_e(v1.z, v1.w, v2.x);
        float h3 = lj_half_e(v2.y, v2.z, v2.w);

        unsigned u;
        u = (unsigned)ia.x - lo; if (u < BUCKET) atomicAdd(&acc[u], h0);
        u = (unsigned)ib.x - lo; if (u < BUCKET) atomicAdd(&acc[u], h0);
        u = (unsigned)ia.y - lo; if (u < BUCKET) atomicAdd(&acc[u], h1);
        u = (unsigned)ib.y - lo; if (u < BUCKET) atomicAdd(&acc[u], h1);
        u = (unsigned)ia.z - lo; if (u < BUCKET) atomicAdd(&acc[u], h2);
        u = (unsigned)ib.z - lo; if (u < BUCKET) atomicAdd(&acc[u], h2);
        u = (unsigned)ia.w - lo; if (u < BUCKET) atomicAdd(&acc[u], h3);
        u = (unsigned)ib.w - lo; if (u < BUCKET) atomicAdd(&acc[u], h3);
    }

    // Edge-count tail (n_edges % 4 != 0): last slice, LDS path.
    if ((n_edges & 3) && m == members - 1) {
        for (long long e = quads * 4 + threadIdx.x; e < n_edges; e += BLOCK_T) {
            float x = dist[e * 3 + 0];
            float y = dist[e * 3 + 1];
            float z = dist[e * 3 + 2];
            float h = lj_half_e(x, y, z);
            unsigned u;
            u = (unsigned)atom_a[e] - lo; if (u < BUCKET) atomicAdd(&acc[u], h);
            u = (unsigned)atom_b[e] - lo; if (u < BUCKET) atomicAdd(&acc[u], h);
        }
    }
    __syncthreads();

    float* dst = ws + (size_t)(g * members + m) * BUCKET;
    for (int i = threadIdx.x; i < BUCKET; i += BLOCK_T) dst[i] = acc[i];
}

// out[a] = gacc[a] + sum over the `members` partials of a's group.
__global__ void reduce_groups(const float* __restrict__ ws,
                              const float* __restrict__ gacc,
                              float* __restrict__ out,
                              int members, int n_atoms) {
    int i = blockIdx.x * blockDim.x + threadIdx.x;
    if (i >= n_atoms) return;
    int g = i / BUCKET;
    int off = i - g * BUCKET;
    const float* base = ws + ((size_t)g * members) * BUCKET + off;
    float s = gacc[i];
    #pragma unroll 4
    for (int b = 0; b < members; ++b) s += base[(size_t)b * BUCKET];
    out[i] = s;
}

// Fallback (ws far too small): device-scope atomics straight into out. Slow but correct.
__global__ void lj_scatter_direct(const float* __restrict__ dist,
                                  const int* __restrict__ atom_a,
                                  const int* __restrict__ atom_b,
                                  float* __restrict__ out,
                                  int n_edges) {
    int t = blockIdx.x * blockDim.x + threadIdx.x;
    long long e0 = (long long)t * 4;
    if (e0 >= n_edges) return;
    if (e0 + 3 < n_edges) {
        const float4* d4 = (const float4*)(dist) + (size_t)t * 3;
        float4 v0 = d4[0];
        float4 v1 = d4[1];
        float4 v2 = d4[2];
        int4 ia = ((const int4*)atom_a)[t];
        int4 ib = ((const int4*)atom_b)[t];
        float h0 = lj_half_e(v0.x, v0.y, v0.z);
        float h1 = lj_half_e(v0.w, v1.x, v1.y);
        float h2 = lj_half_e(v1.z, v1.w, v2.x);
        float h3 = lj_half_e(v2.y, v2.z, v2.w);
        atomicAdd(&out[ia.x], h0);
        atomicAdd(&out[ib.x], h0);
        atomicAdd(&out[ia.y], h1);
        atomicAdd(&out[ib.y], h1);
        atomicAdd(&out[ia.z], h2);
        atomicAdd(&out[ib.z], h2);
        atomicAdd(&out[ia.w], h3);
        atomicAdd(&out[ib.w], h3);
    } else {
        for (long long e = e0; e < n_edges; ++e) {
            float x = dist[e * 3 + 0];
            float y = dist[e * 3 + 1];
            float z = dist[e * 3 + 2];
            float h = lj_half_e(x, y, z);
            atomicAdd(&out[atom_a[e]], h);
            atomicAdd(&out[atom_b[e]], h);
        }
    }
}

extern "C" void kernel_launch(void* const* d_in, const int* in_sizes, int n_in,
                              void* d_out, int out_size, void* d_ws, size_t ws_size,
                              hipStream_t stream) {
    const float* dist = (const float*)d_in[0];
    const int* atom_a = (const int*)d_in[1];
    const int* atom_b = (const int*)d_in[2];
    float* out = (float*)d_out;

    int n_edges = in_sizes[1];
    int n_atoms = out_size;

    // ws layout: partials [GROUPS*members][BUCKET] then gacc [n_atoms].
    size_t gacc_bytes = (size_t)n_atoms * sizeof(float);
    size_t per_member = (size_t)GROUPS * BUCKET * sizeof(float);
    size_t avail = (ws_size > gacc_bytes) ? (ws_size - gacc_bytes) : 0;
    int members = (int)(avail / per_member);
    if (members > MAX_MEMBERS) members = MAX_MEMBERS;
    bool range_ok = ((long long)GROUPS * BUCKET >= (long long)n_atoms);

    if (members >= 8 && range_ok) {
        float* ws = (float*)d_ws;
        float* gacc = ws + (size_t)GROUPS * members * BUCKET;
        hipMemsetAsync(gacc, 0, gacc_bytes, stream);
        lj_gather_hybrid<<<GROUPS * members, BLOCK_T, 0, stream>>>(
            dist, atom_a, atom_b, ws, gacc, members, n_edges);
        int rblock = 256;
        int rgrid = (n_atoms + rblock - 1) / rblock;
        reduce_groups<<<rgrid, rblock, 0, stream>>>(ws, gacc, out, members, n_atoms);
    } else {
        hipMemsetAsync(d_out, 0, (size_t)n_atoms * sizeof(float), stream);
        int n_quads = (n_edges + 3) / 4;
        int block = 256;
        int grid = (n_quads + block - 1) / block;
        lj_scatter_direct<<<grid, block, 0, stream>>>(dist, atom_a, atom_b, out, n_edges);
    }
}